// Round 6
// baseline (346.344 us; speedup 1.0000x reference)
//
#include <hip/hip_runtime.h>
#include <stdint.h>

#define N_NODES   50000
#define N_EDGES   800000
#define IN_DIM    128
#define OUT_DIM   128
#define NUM_RELS  8
#define THREADS   256

typedef _Float16 half_t;
typedef _Float16 half2v __attribute__((ext_vector_type(2)));
typedef _Float16 half8 __attribute__((ext_vector_type(8)));
typedef float floatx4 __attribute__((ext_vector_type(4)));

// ============ plan (round 5 resubmit): aggregate-then-transform ============
// out[d] = sum_r ( sum_{e: dst=d, rel=r} w_e * feat[src_e] ) @ W[r]
// 1. memset head = -1
// 2. prep: WfT[n][r*128+k] f16 transpose  +  linked-list bucket build
//    next[e] = atomicExch(&head[dst[e]], e)   (no scans, no scatter, no rank)
// 3. agg: wave per dst walks its list; acc h[8][128] in 16 f32 regs/lane
//    (rel is wave-uniform -> static-index switch; feat 25.6MB = LLC-resident
//     so the random reads that used to hit 102MB y2 in HBM now hit cache)
// 4. gemm2: out[50000x128] = h[50000x1024] @ Wflat[1024x128], MFMA,
//    fragment/staging/swizzle mapping cloned from the round-7-proven gemm.
// Traffic: ~310MB random (old gather+gemm) -> ~230MB mostly-sequential.
// (round-5 bench was an infra failure: "container failed twice", no kernel
//  error; source re-audited for hang/OOB/capture rules -- clean. Resubmit.)

// ---- ws layout (bytes): 106,062,144 total (< proven 109,462,464)
#define WS_H      0                               // h    : 50000 x 1024 f16 (102,400,000)
#define WS_WFT    102400000                       // WfT  : 128 x 1024 f16 (262,144)
#define WS_HEAD   102662144                       // head : 50000 i32 (200,000)
#define WS_NEXT   102862144                       // next : N_EDGES i32 (3,200,000)
#define WS_NEED3  (size_t)106062144

#define LIST_BLOCKS (N_EDGES / 256)               // 3125 exactly

// ---- prep: WfT transpose-convert (512 blocks) + linked-list build (3125 blocks)
__global__ void prep_kernel(const float* __restrict__ rel_emb, half_t* __restrict__ WfT,
                            const int* __restrict__ dst, int* __restrict__ head,
                            int* __restrict__ next) {
    int b = blockIdx.x;
    if (b < 512) {                                 // 512*256 = 131072 = 8*128*128 exactly
        int t = b * 256 + threadIdx.x;             // t = r*16384 + k*128 + n
        int r = t >> 14, k = (t >> 7) & 127, n = t & 127;
        WfT[(size_t)n * 1024 + r * 128 + k] = (half_t)rel_emb[t];
    } else {
        int i = (b - 512) * 256 + threadIdx.x;     // < 800000 exactly
        next[i] = atomicExch(&head[dst[i]], i);
    }
}

// ---- agg: wave per dst; walk list; h[g][r*128+k] = sum w*feat[src][k]
// lane covers k = {2*lane, 2*lane+1} for all 8 rels -> 16 f32 accumulators.
__global__ __launch_bounds__(THREADS) void agg_kernel(
    const float* __restrict__ feat, const float* __restrict__ ew,
    const int* __restrict__ src, const int* __restrict__ rel,
    const int* __restrict__ head, const int* __restrict__ next,
    half_t* __restrict__ h) {
    int g = blockIdx.x * 4 + (threadIdx.x >> 6);   // 12500 blocks -> g < 50000
    int lane = threadIdx.x & 63;

    float a0x = 0.f, a0y = 0.f, a1x = 0.f, a1y = 0.f;
    float a2x = 0.f, a2y = 0.f, a3x = 0.f, a3y = 0.f;
    float a4x = 0.f, a4y = 0.f, a5x = 0.f, a5y = 0.f;
    float a6x = 0.f, a6y = 0.f, a7x = 0.f, a7y = 0.f;

    int e = head[g];                               // wave-uniform
    while (e >= 0) {
        int nx  = next[e];                         // chase next hop early
        int sr  = src[e];
        int re  = rel[e];                          // wave-uniform -> scalar branch
        float w = ew[e];
        float2 f = *(const float2*)(feat + (size_t)sr * 128 + lane * 2);
        float wx = w * f.x, wy = w * f.y;
        switch (re) {                              // static acc indexing (no scratch)
            case 0: a0x += wx; a0y += wy; break;
            case 1: a1x += wx; a1y += wy; break;
            case 2: a2x += wx; a2y += wy; break;
            case 3: a3x += wx; a3y += wy; break;
            case 4: a4x += wx; a4y += wy; break;
            case 5: a5x += wx; a5y += wy; break;
            case 6: a6x += wx; a6y += wy; break;
            default: a7x += wx; a7y += wy; break;
        }
        e = nx;
    }

    half_t* hb = h + (size_t)g * 1024 + lane * 2;
    *(half2v*)(hb + 0 * 128) = (half2v){(half_t)a0x, (half_t)a0y};
    *(half2v*)(hb + 1 * 128) = (half2v){(half_t)a1x, (half_t)a1y};
    *(half2v*)(hb + 2 * 128) = (half2v){(half_t)a2x, (half_t)a2y};
    *(half2v*)(hb + 3 * 128) = (half2v){(half_t)a3x, (half_t)a3y};
    *(half2v*)(hb + 4 * 128) = (half2v){(half_t)a4x, (half_t)a4y};
    *(half2v*)(hb + 5 * 128) = (half2v){(half_t)a5x, (half_t)a5y};
    *(half2v*)(hb + 6 * 128) = (half2v){(half_t)a6x, (half_t)a6y};
    *(half2v*)(hb + 7 * 128) = (half2v){(half_t)a7x, (half_t)a7y};
}

// ---- gemm2: out[d][n] = sum_k h[d][k] * Wflat[k][n]
// Mirrors the proven gemm fragment mapping exactly:
//   a = WfT row frag (row = output col n), b = h row frag (row = dst d),
//   C: out[d(l16)][nt*16 + q*4 + j] = acc[nt][j]
// Block = 64 dsts x 128 cols; K-loop of 8 chunks (128 k each) staged in LDS
// with the same half8-granular XOR swizzle as the proven kernel.
template<bool GUARD>
__device__ __forceinline__ void gemm2_body(const half_t* __restrict__ h,
                                           const half_t* __restrict__ WfT,
                                           half_t* __restrict__ Ws,
                                           float* __restrict__ out,
                                           int m0, int wave, int lane, int t) {
    const int q = lane >> 4, l16 = lane & 15;
    const int d = m0 + wave * 16 + l16;
    const bool ok = !GUARD || d < N_NODES;
    const half_t* hb = h + (size_t)d * 1024;

    floatx4 acc[8];
    #pragma unroll
    for (int nt = 0; nt < 8; nt++) acc[nt] = (floatx4){0.f, 0.f, 0.f, 0.f};

    #pragma unroll
    for (int kc = 0; kc < 8; kc++) {
        // b-frags for this k-chunk (issued before barriers -> in flight during stage)
        half8 bf[4];
        #pragma unroll
        for (int kk = 0; kk < 4; kk++) {
            uint4 v = {0u, 0u, 0u, 0u};
            if (ok) v = *(const uint4*)(hb + kc * 128 + kk * 32 + q * 8);
            bf[kk] = *(half8*)&v;
        }
        __syncthreads();                           // prev chunk compute done
        for (int i = t; i < 2048; i += THREADS) {  // stage WfT chunk kc (swizzled)
            int row = i >> 4, lc = i & 15;
            int phys = lc ^ (row & 7);
            *(uint4*)&Ws[row * 128 + phys * 8] =
                *(const uint4*)(WfT + (size_t)row * 1024 + kc * 128 + lc * 8);
        }
        __syncthreads();
        #pragma unroll
        for (int kk = 0; kk < 4; kk++)
            #pragma unroll
            for (int nt = 0; nt < 8; nt++) {
                int row = nt * 16 + l16;
                int phys = (kk * 4 + q) ^ (l16 & 7);
                half8 a = *(const half8*)(Ws + row * 128 + phys * 8);
                acc[nt] = __builtin_amdgcn_mfma_f32_16x16x32_f16(a, bf[kk], acc[nt], 0, 0, 0);
            }
    }

    if (ok) {
        float* ob = out + (size_t)d * 128;
        #pragma unroll
        for (int nt = 0; nt < 8; nt++) {
            float4 v;
            v.x = acc[nt][0]; v.y = acc[nt][1]; v.z = acc[nt][2]; v.w = acc[nt][3];
            *(float4*)(ob + nt * 16 + q * 4) = v;
        }
    }
}

#define G2_BLOCKS ((N_NODES + 63) / 64)            // 782
__global__ __launch_bounds__(THREADS) void gemm2_kernel(
    const half_t* __restrict__ h, const half_t* __restrict__ WfT,
    float* __restrict__ out) {
    __shared__ half_t Ws[128 * 128];               // 32 KB -> 5 blocks/CU cap
    const int m0 = blockIdx.x * 64;
    const int t = threadIdx.x;
    const int wave = t >> 6, lane = t & 63;
    if (m0 + 64 <= N_NODES)
        gemm2_body<false>(h, WfT, Ws, out, m0, wave, lane, t);
    else
        gemm2_body<true>(h, WfT, Ws, out, m0, wave, lane, t);
}

// ---- fallback (tiny ws): wave-per-edge direct with atomics
__global__ void naive_kernel(const float* __restrict__ feat, const float* __restrict__ rel_emb,
                             const float* __restrict__ ew, const int* __restrict__ src,
                             const int* __restrict__ dst, const int* __restrict__ rel,
                             float* __restrict__ out) {
    int wave = (blockIdx.x * blockDim.x + threadIdx.x) >> 6;
    int lane = threadIdx.x & 63;
    if (wave >= N_EDGES) return;
    const float* f = feat + (size_t)src[wave] * IN_DIM;
    const float* W = rel_emb + (size_t)rel[wave] * IN_DIM * OUT_DIM;
    float w = ew[wave];
    float a0 = 0.f, a1 = 0.f;
    for (int k = 0; k < IN_DIM; k++) {
        float fv = f[k];
        a0 += fv * W[k * OUT_DIM + lane];
        a1 += fv * W[k * OUT_DIM + 64 + lane];
    }
    int d = dst[wave];
    atomicAdd(&out[(size_t)d * OUT_DIM + lane], a0 * w);
    atomicAdd(&out[(size_t)d * OUT_DIM + 64 + lane], a1 * w);
}

extern "C" void kernel_launch(void* const* d_in, const int* in_sizes, int n_in,
                              void* d_out, int out_size, void* d_ws, size_t ws_size,
                              hipStream_t stream) {
    const float* feat    = (const float*)d_in[0];
    const float* rel_emb = (const float*)d_in[1];
    const float* ew      = (const float*)d_in[2];
    const int*   src     = (const int*)d_in[3];
    const int*   dst     = (const int*)d_in[4];
    const int*   rel     = (const int*)d_in[5];
    float* out = (float*)d_out;

    if (ws_size >= WS_NEED3) {
        char* ws = (char*)d_ws;
        half_t* h    = (half_t*)(ws + WS_H);
        half_t* WfT  = (half_t*)(ws + WS_WFT);
        int*    head = (int*)(ws + WS_HEAD);
        int*    next = (int*)(ws + WS_NEXT);

        hipMemsetAsync(head, 0xFF, (size_t)N_NODES * 4, stream);   // head = -1
        prep_kernel<<<512 + LIST_BLOCKS, THREADS, 0, stream>>>(rel_emb, WfT, dst, head, next);
        agg_kernel<<<N_NODES / 4, THREADS, 0, stream>>>(feat, ew, src, rel, head, next, h);
        gemm2_kernel<<<G2_BLOCKS, THREADS, 0, stream>>>(h, WfT, out);
    } else {
        hipMemsetAsync(d_out, 0, (size_t)out_size * sizeof(float), stream);
        const long long total = (long long)N_EDGES * 64;
        const int blocks = (int)((total + THREADS - 1) / THREADS);
        naive_kernel<<<blocks, THREADS, 0, stream>>>(feat, rel_emb, ew, src, dst, rel, out);
    }
}

// Round 7
// 307.593 us; speedup vs baseline: 1.1260x; 1.1260x over previous
//
#include <hip/hip_runtime.h>
#include <stdint.h>

#define N_NODES   50000
#define N_EDGES   800000
#define IN_DIM    128
#define OUT_DIM   128
#define NUM_RELS  8
#define THREADS   256

typedef _Float16 half_t;
typedef _Float16 half2v __attribute__((ext_vector_type(2)));
typedef _Float16 half8 __attribute__((ext_vector_type(8)));
typedef float floatx4 __attribute__((ext_vector_type(4)));

// ============ plan (round 7): CSR front-end + aggregate-then-transform ============
// Round-6 lesson: list-walk agg fetched 356MB (4 random index lines/edge + f32
// feat rows); L3 did NOT absorb the 25.6MB feat region. Fix both:
//   - CSR rec[] (round-4 proven rank/scan/scatter) -> agg reads edges SEQUENTIALLY
//   - featH f16 (12.8MB) -> halves per-edge feat bytes
// Pipeline: memset(hist) -> prep(WfT transpose + featH convert + rank capture)
//   -> scans(off) -> scatter(rec, atomic-free) -> agg(wave/dst, 16 f32 acc)
//   -> gemm2(out = h @ Wflat, MFMA, round-6 correctness-proven)
// rank(3.2MB)+featH(12.8MB) live in d_out scratch (dead until gemm2 writes).

#define NBINS3    N_NODES                         // 50000
#define NB3       ((NBINS3 + 1023) / 1024)        // 49

// ---- ws layout (bytes): exactly the proven 109,462,464 budget
#define WS_H      0                               // h    : 50000 x 1024 f16 (102,400,000)
#define WS_WFT    102400000                       // WfT  : 128 x 1024 f16 (262,144)
#define WS_REC    102662144                       // rec  : N_EDGES uint2 (6,400,000)
#define WS_OFF    109062144                       // off  : 50001 i32 (pad 200,064)
#define WS_HIST   109262208                       // hist : 50000 i32 (200,000)
#define WS_BSUM   109462208                       // bsum : 49 i32 (pad 256)
#define WS_NEED   (size_t)109462464

// d_out scratch offsets (out = 25.6MB, dead until gemm2)
#define DO_RANK   0                               // rank : N_EDGES i32 (3,200,000)
#define DO_FEATH  3200000                         // featH: 50000 x 128 f16 (12,800,000)

#define CONV_BLOCKS 3125                          // 800000 threads x 8 halfs = 6.4M elems
#define RANK_BLOCKS 3125                          // 800000 threads x 1 edge
#define PREP_BLOCKS (512 + CONV_BLOCKS + RANK_BLOCKS)   // 6762

// ---- prep: WfT transpose (512) + featH convert (3125) + rank capture (3125)
__global__ void prep_kernel(const float* __restrict__ rel_emb, half_t* __restrict__ WfT,
                            const float* __restrict__ feat, half_t* __restrict__ featH,
                            const int* __restrict__ dst, int* __restrict__ hist,
                            int* __restrict__ rank) {
    int b = blockIdx.x;
    if (b < 512) {                                 // 512*256 = 131072 = 8*128*128 exactly
        int t = b * 256 + threadIdx.x;             // t = r*16384 + k*128 + n
        int r = t >> 14, k = (t >> 7) & 127, n = t & 127;
        WfT[(size_t)n * 1024 + r * 128 + k] = (half_t)rel_emb[t];   // round-6 proven
    } else if (b < 512 + CONV_BLOCKS) {
        int t = (b - 512) * 256 + threadIdx.x;     // 0..799999, 8 halfs each
        const float* fb = feat + (size_t)t * 8;
        float4 v0 = *(const float4*)fb;
        float4 v1 = *(const float4*)(fb + 4);
        half8 hv;
        hv[0] = (half_t)v0.x; hv[1] = (half_t)v0.y; hv[2] = (half_t)v0.z; hv[3] = (half_t)v0.w;
        hv[4] = (half_t)v1.x; hv[5] = (half_t)v1.y; hv[6] = (half_t)v1.z; hv[7] = (half_t)v1.w;
        *(half8*)(featH + (size_t)t * 8) = hv;
    } else {
        int i = (b - 512 - CONV_BLOCKS) * 256 + threadIdx.x;   // < 800000 exactly
        rank[i] = atomicAdd(&hist[dst[i]], 1);     // round-4 proven rank capture
    }
}

// ---- scans (round-2..4 proven verbatim)
__global__ void scan1_kernel(const int* __restrict__ hist, int* __restrict__ bsum) {
    __shared__ int sh[256];
    int b = blockIdx.x, t = threadIdx.x;
    int i0 = b * 1024 + t * 4;
    int s = 0;
    #pragma unroll
    for (int j = 0; j < 4; j++) { int idx = i0 + j; if (idx < NBINS3) s += hist[idx]; }
    sh[t] = s; __syncthreads();
    for (int o = 128; o > 0; o >>= 1) { if (t < o) sh[t] += sh[t + o]; __syncthreads(); }
    if (t == 0) bsum[b] = sh[0];
}

__global__ void scan2_kernel(int* __restrict__ bsum, int* __restrict__ off) {
    __shared__ int sh[64];
    int t = threadIdx.x;
    int v = (t < NB3) ? bsum[t] : 0;
    sh[t] = v; __syncthreads();
    for (int o = 1; o < 64; o <<= 1) {
        int x = (t >= o) ? sh[t - o] : 0;
        __syncthreads();
        sh[t] += x;
        __syncthreads();
    }
    if (t < NB3) bsum[t] = sh[t] - v;
    if (t == 0) off[NBINS3] = N_EDGES;
}

__global__ void scan3_kernel(const int* __restrict__ hist, const int* __restrict__ boff,
                             int* __restrict__ off, int* __restrict__ cursors) {
    __shared__ int sh[256];
    int b = blockIdx.x, t = threadIdx.x;
    int i0 = b * 1024 + t * 4;
    int v[4]; int s = 0;
    #pragma unroll
    for (int j = 0; j < 4; j++) { int idx = i0 + j; v[j] = (idx < NBINS3) ? hist[idx] : 0; s += v[j]; }
    sh[t] = s; __syncthreads();
    for (int o = 1; o < 256; o <<= 1) {
        int x = (t >= o) ? sh[t - o] : 0;
        __syncthreads();
        sh[t] += x;
        __syncthreads();
    }
    int run = sh[t] - s + boff[b];
    #pragma unroll
    for (int j = 0; j < 4; j++) {
        int idx = i0 + j;
        if (idx < NBINS3) { off[idx] = run; cursors[idx] = run; }
        run += v[j];
    }
}

// ---- scatter: atomic-free (rank precomputed), fire-and-forget 8B records
__global__ __launch_bounds__(THREADS) void scatter_kernel(
    const int* __restrict__ dst, const int* __restrict__ src,
    const int* __restrict__ rel, const float* __restrict__ ew,
    const int* __restrict__ rank, const int* __restrict__ off,
    uint2* __restrict__ rec) {
    int i = blockIdx.x * 256 + threadIdx.x;        // 3125*256 = 800000 exactly
    int d = dst[i];
    int pos = off[d] + rank[i];
    uint2 v;
    v.x = (unsigned)(src[i] * 8 + rel[i]);         // src < 2^19, rel < 8
    v.y = __float_as_uint(ew[i]);
    rec[pos] = v;
}

// ---- agg: wave per dst; SEQUENTIAL rec reads; random featH reads (12.8MB region)
// accumulate h[8][128] in 16 f32 regs/lane (round-6 proven layout), MLP=4 edges.
__global__ __launch_bounds__(THREADS) void agg_kernel(
    const half_t* __restrict__ featH, const uint2* __restrict__ rec,
    const int* __restrict__ off, half_t* __restrict__ h) {
    int g = blockIdx.x * 4 + (threadIdx.x >> 6);   // 12500 blocks -> g < 50000
    int lane = threadIdx.x & 63;
    int beg = off[g], end = off[g + 1];

    float a0x = 0.f, a0y = 0.f, a1x = 0.f, a1y = 0.f;
    float a2x = 0.f, a2y = 0.f, a3x = 0.f, a3y = 0.f;
    float a4x = 0.f, a4y = 0.f, a5x = 0.f, a5y = 0.f;
    float a6x = 0.f, a6y = 0.f, a7x = 0.f, a7y = 0.f;

    const half_t* fb = featH + lane * 2;

#define ACCUM(RE, W, F) do {                                   \
        float wx_ = (W) * (float)(F)[0];                       \
        float wy_ = (W) * (float)(F)[1];                       \
        switch (RE) {                                          \
            case 0: a0x += wx_; a0y += wy_; break;             \
            case 1: a1x += wx_; a1y += wy_; break;             \
            case 2: a2x += wx_; a2y += wy_; break;             \
            case 3: a3x += wx_; a3y += wy_; break;             \
            case 4: a4x += wx_; a4y += wy_; break;             \
            case 5: a5x += wx_; a5y += wy_; break;             \
            case 6: a6x += wx_; a6y += wy_; break;             \
            default: a7x += wx_; a7y += wy_; break;            \
        } } while (0)

    int e = beg;
    for (; e + 4 <= end; e += 4) {                 // 4 independent featH reads in flight
        uint2 r0 = rec[e], r1 = rec[e + 1], r2 = rec[e + 2], r3 = rec[e + 3];
        half2v f0 = *(const half2v*)(fb + (size_t)(r0.x >> 3) * 128);
        half2v f1 = *(const half2v*)(fb + (size_t)(r1.x >> 3) * 128);
        half2v f2 = *(const half2v*)(fb + (size_t)(r2.x >> 3) * 128);
        half2v f3 = *(const half2v*)(fb + (size_t)(r3.x >> 3) * 128);
        ACCUM(r0.x & 7, __uint_as_float(r0.y), f0);
        ACCUM(r1.x & 7, __uint_as_float(r1.y), f1);
        ACCUM(r2.x & 7, __uint_as_float(r2.y), f2);
        ACCUM(r3.x & 7, __uint_as_float(r3.y), f3);
    }
    for (; e < end; e++) {
        uint2 r0 = rec[e];
        half2v f0 = *(const half2v*)(fb + (size_t)(r0.x >> 3) * 128);
        ACCUM(r0.x & 7, __uint_as_float(r0.y), f0);
    }
#undef ACCUM

    half_t* hb = h + (size_t)g * 1024 + lane * 2;  // round-6 proven store layout
    *(half2v*)(hb + 0 * 128) = (half2v){(half_t)a0x, (half_t)a0y};
    *(half2v*)(hb + 1 * 128) = (half2v){(half_t)a1x, (half_t)a1y};
    *(half2v*)(hb + 2 * 128) = (half2v){(half_t)a2x, (half_t)a2y};
    *(half2v*)(hb + 3 * 128) = (half2v){(half_t)a3x, (half_t)a3y};
    *(half2v*)(hb + 4 * 128) = (half2v){(half_t)a4x, (half_t)a4y};
    *(half2v*)(hb + 5 * 128) = (half2v){(half_t)a5x, (half_t)a5y};
    *(half2v*)(hb + 6 * 128) = (half2v){(half_t)a6x, (half_t)a6y};
    *(half2v*)(hb + 7 * 128) = (half2v){(half_t)a7x, (half_t)a7y};
}

// ---- gemm2: out = h[50000x1024] @ Wflat[1024x128]  (round-6 correctness-proven)
template<bool GUARD>
__device__ __forceinline__ void gemm2_body(const half_t* __restrict__ h,
                                           const half_t* __restrict__ WfT,
                                           half_t* __restrict__ Ws,
                                           float* __restrict__ out,
                                           int m0, int wave, int lane, int t) {
    const int q = lane >> 4, l16 = lane & 15;
    const int d = m0 + wave * 16 + l16;
    const bool ok = !GUARD || d < N_NODES;
    const half_t* hb = h + (size_t)d * 1024;

    floatx4 acc[8];
    #pragma unroll
    for (int nt = 0; nt < 8; nt++) acc[nt] = (floatx4){0.f, 0.f, 0.f, 0.f};

    #pragma unroll
    for (int kc = 0; kc < 8; kc++) {
        half8 bf[4];
        #pragma unroll
        for (int kk = 0; kk < 4; kk++) {
            uint4 v = {0u, 0u, 0u, 0u};
            if (ok) v = *(const uint4*)(hb + kc * 128 + kk * 32 + q * 8);
            bf[kk] = *(half8*)&v;
        }
        __syncthreads();
        for (int i = t; i < 2048; i += THREADS) {
            int row = i >> 4, lc = i & 15;
            int phys = lc ^ (row & 7);
            *(uint4*)&Ws[row * 128 + phys * 8] =
                *(const uint4*)(WfT + (size_t)row * 1024 + kc * 128 + lc * 8);
        }
        __syncthreads();
        #pragma unroll
        for (int kk = 0; kk < 4; kk++)
            #pragma unroll
            for (int nt = 0; nt < 8; nt++) {
                int row = nt * 16 + l16;
                int phys = (kk * 4 + q) ^ (l16 & 7);
                half8 a = *(const half8*)(Ws + row * 128 + phys * 8);
                acc[nt] = __builtin_amdgcn_mfma_f32_16x16x32_f16(a, bf[kk], acc[nt], 0, 0, 0);
            }
    }

    if (ok) {
        float* ob = out + (size_t)d * 128;
        #pragma unroll
        for (int nt = 0; nt < 8; nt++) {
            float4 v;
            v.x = acc[nt][0]; v.y = acc[nt][1]; v.z = acc[nt][2]; v.w = acc[nt][3];
            *(float4*)(ob + nt * 16 + q * 4) = v;
        }
    }
}

#define G2_BLOCKS ((N_NODES + 63) / 64)            // 782
__global__ __launch_bounds__(THREADS) void gemm2_kernel(
    const half_t* __restrict__ h, const half_t* __restrict__ WfT,
    float* __restrict__ out) {
    __shared__ half_t Ws[128 * 128];               // 32 KB -> 5 blocks/CU cap
    const int m0 = blockIdx.x * 64;
    const int t = threadIdx.x;
    const int wave = t >> 6, lane = t & 63;
    if (m0 + 64 <= N_NODES)
        gemm2_body<false>(h, WfT, Ws, out, m0, wave, lane, t);
    else
        gemm2_body<true>(h, WfT, Ws, out, m0, wave, lane, t);
}

// ---- fallback (tiny ws): wave-per-edge direct with atomics
__global__ void naive_kernel(const float* __restrict__ feat, const float* __restrict__ rel_emb,
                             const float* __restrict__ ew, const int* __restrict__ src,
                             const int* __restrict__ dst, const int* __restrict__ rel,
                             float* __restrict__ out) {
    int wave = (blockIdx.x * blockDim.x + threadIdx.x) >> 6;
    int lane = threadIdx.x & 63;
    if (wave >= N_EDGES) return;
    const float* f = feat + (size_t)src[wave] * IN_DIM;
    const float* W = rel_emb + (size_t)rel[wave] * IN_DIM * OUT_DIM;
    float w = ew[wave];
    float a0 = 0.f, a1 = 0.f;
    for (int k = 0; k < IN_DIM; k++) {
        float fv = f[k];
        a0 += fv * W[k * OUT_DIM + lane];
        a1 += fv * W[k * OUT_DIM + 64 + lane];
    }
    int d = dst[wave];
    atomicAdd(&out[(size_t)d * OUT_DIM + lane], a0 * w);
    atomicAdd(&out[(size_t)d * OUT_DIM + 64 + lane], a1 * w);
}

extern "C" void kernel_launch(void* const* d_in, const int* in_sizes, int n_in,
                              void* d_out, int out_size, void* d_ws, size_t ws_size,
                              hipStream_t stream) {
    const float* feat    = (const float*)d_in[0];
    const float* rel_emb = (const float*)d_in[1];
    const float* ew      = (const float*)d_in[2];
    const int*   src     = (const int*)d_in[3];
    const int*   dst     = (const int*)d_in[4];
    const int*   rel     = (const int*)d_in[5];
    float* out = (float*)d_out;

    if (ws_size >= WS_NEED) {
        char* ws = (char*)d_ws;
        half_t* h    = (half_t*)(ws + WS_H);
        half_t* WfT  = (half_t*)(ws + WS_WFT);
        uint2*  rec  = (uint2*)(ws + WS_REC);
        int*    off  = (int*)(ws + WS_OFF);
        int*    hist = (int*)(ws + WS_HIST);
        int*    bsum = (int*)(ws + WS_BSUM);
        // d_out scratch (dead until gemm2 writes it)
        int*    rank  = (int*)((char*)d_out + DO_RANK);
        half_t* featH = (half_t*)((char*)d_out + DO_FEATH);

        hipMemsetAsync(hist, 0, (size_t)NBINS3 * 4, stream);
        prep_kernel<<<PREP_BLOCKS, THREADS, 0, stream>>>(rel_emb, WfT, feat, featH,
                                                         dst, hist, rank);
        scan1_kernel<<<NB3, 256, 0, stream>>>(hist, bsum);
        scan2_kernel<<<1, 64, 0, stream>>>(bsum, off);
        scan3_kernel<<<NB3, 256, 0, stream>>>(hist, bsum, off, hist);  // cursors unused
        scatter_kernel<<<RANK_BLOCKS, THREADS, 0, stream>>>(dst, src, rel, ew,
                                                            rank, off, rec);
        agg_kernel<<<N_NODES / 4, THREADS, 0, stream>>>(featH, rec, off, h);
        gemm2_kernel<<<G2_BLOCKS, THREADS, 0, stream>>>(h, WfT, out);
    } else {
        hipMemsetAsync(d_out, 0, (size_t)out_size * sizeof(float), stream);
        const long long total = (long long)N_EDGES * 64;
        const int blocks = (int)((total + THREADS - 1) / THREADS);
        naive_kernel<<<blocks, THREADS, 0, stream>>>(feat, rel_emb, ew, src, dst, rel, out);
    }
}

// Round 8
// 294.073 us; speedup vs baseline: 1.1777x; 1.0460x over previous
//
#include <hip/hip_runtime.h>
#include <stdint.h>

#define N_NODES   50000
#define N_EDGES   800000
#define IN_DIM    128
#define OUT_DIM   128
#define NUM_RELS  8
#define THREADS   256

typedef _Float16 half_t;
typedef _Float16 half2v __attribute__((ext_vector_type(2)));
typedef _Float16 half8 __attribute__((ext_vector_type(8)));
typedef float floatx4 __attribute__((ext_vector_type(4)));

// ============ plan (round 8): CSR front-end + agg + WAVE-TILE gemm2 ============
// Round-7 profile: gemm2 = 104.6us, VGPR 220 (full kc-unroll hoisted 128 VGPRs
// of loads), Occupancy 8.9%, 3.2M LDS conflicts, 2 barriers/chunk, 782 blocks
// -> pure latency bound (MFMA floor is ~6us). Fix: barrier-free independent
// wave tiles (32 dst x 64 col, K=1024), A-frags direct from L2-hot WfT
// (256KB, no LDS), B-frags from own h rows. 3126 wave-tiles, ~150 VGPR,
// zero LDS, zero barriers. Fragment byte-mapping identical to proven gemm2.
// Front-end (prep/scans/scatter/agg) unchanged from round 7.

#define NBINS3    N_NODES                         // 50000
#define NB3       ((NBINS3 + 1023) / 1024)        // 49

// ---- ws layout (bytes): exactly the proven 109,462,464 budget
#define WS_H      0                               // h    : 50000 x 1024 f16 (102,400,000)
#define WS_WFT    102400000                       // WfT  : 128 x 1024 f16 (262,144)
#define WS_REC    102662144                       // rec  : N_EDGES uint2 (6,400,000)
#define WS_OFF    109062144                       // off  : 50001 i32 (pad 200,064)
#define WS_HIST   109262208                       // hist : 50000 i32 (200,000)
#define WS_BSUM   109462208                       // bsum : 49 i32 (pad 256)
#define WS_NEED   (size_t)109462464

// d_out scratch offsets (out = 25.6MB, dead until gemm2)
#define DO_RANK   0                               // rank : N_EDGES i32 (3,200,000)
#define DO_FEATH  3200000                         // featH: 50000 x 128 f16 (12,800,000)

#define CONV_BLOCKS 3125                          // 800000 threads x 8 halfs = 6.4M elems
#define RANK_BLOCKS 3125                          // 800000 threads x 1 edge
#define PREP_BLOCKS (512 + CONV_BLOCKS + RANK_BLOCKS)   // 6762

// ---- prep: WfT transpose (512) + featH convert (3125) + rank capture (3125)
__global__ void prep_kernel(const float* __restrict__ rel_emb, half_t* __restrict__ WfT,
                            const float* __restrict__ feat, half_t* __restrict__ featH,
                            const int* __restrict__ dst, int* __restrict__ hist,
                            int* __restrict__ rank) {
    int b = blockIdx.x;
    if (b < 512) {                                 // 512*256 = 131072 = 8*128*128 exactly
        int t = b * 256 + threadIdx.x;             // t = r*16384 + k*128 + n
        int r = t >> 14, k = (t >> 7) & 127, n = t & 127;
        WfT[(size_t)n * 1024 + r * 128 + k] = (half_t)rel_emb[t];   // round-6 proven
    } else if (b < 512 + CONV_BLOCKS) {
        int t = (b - 512) * 256 + threadIdx.x;     // 0..799999, 8 halfs each
        const float* fb = feat + (size_t)t * 8;
        float4 v0 = *(const float4*)fb;
        float4 v1 = *(const float4*)(fb + 4);
        half8 hv;
        hv[0] = (half_t)v0.x; hv[1] = (half_t)v0.y; hv[2] = (half_t)v0.z; hv[3] = (half_t)v0.w;
        hv[4] = (half_t)v1.x; hv[5] = (half_t)v1.y; hv[6] = (half_t)v1.z; hv[7] = (half_t)v1.w;
        *(half8*)(featH + (size_t)t * 8) = hv;
    } else {
        int i = (b - 512 - CONV_BLOCKS) * 256 + threadIdx.x;   // < 800000 exactly
        rank[i] = atomicAdd(&hist[dst[i]], 1);     // round-4 proven rank capture
    }
}

// ---- scans (round-2..4 proven verbatim)
__global__ void scan1_kernel(const int* __restrict__ hist, int* __restrict__ bsum) {
    __shared__ int sh[256];
    int b = blockIdx.x, t = threadIdx.x;
    int i0 = b * 1024 + t * 4;
    int s = 0;
    #pragma unroll
    for (int j = 0; j < 4; j++) { int idx = i0 + j; if (idx < NBINS3) s += hist[idx]; }
    sh[t] = s; __syncthreads();
    for (int o = 128; o > 0; o >>= 1) { if (t < o) sh[t] += sh[t + o]; __syncthreads(); }
    if (t == 0) bsum[b] = sh[0];
}

__global__ void scan2_kernel(int* __restrict__ bsum, int* __restrict__ off) {
    __shared__ int sh[64];
    int t = threadIdx.x;
    int v = (t < NB3) ? bsum[t] : 0;
    sh[t] = v; __syncthreads();
    for (int o = 1; o < 64; o <<= 1) {
        int x = (t >= o) ? sh[t - o] : 0;
        __syncthreads();
        sh[t] += x;
        __syncthreads();
    }
    if (t < NB3) bsum[t] = sh[t] - v;
    if (t == 0) off[NBINS3] = N_EDGES;
}

__global__ void scan3_kernel(const int* __restrict__ hist, const int* __restrict__ boff,
                             int* __restrict__ off, int* __restrict__ cursors) {
    __shared__ int sh[256];
    int b = blockIdx.x, t = threadIdx.x;
    int i0 = b * 1024 + t * 4;
    int v[4]; int s = 0;
    #pragma unroll
    for (int j = 0; j < 4; j++) { int idx = i0 + j; v[j] = (idx < NBINS3) ? hist[idx] : 0; s += v[j]; }
    sh[t] = s; __syncthreads();
    for (int o = 1; o < 256; o <<= 1) {
        int x = (t >= o) ? sh[t - o] : 0;
        __syncthreads();
        sh[t] += x;
        __syncthreads();
    }
    int run = sh[t] - s + boff[b];
    #pragma unroll
    for (int j = 0; j < 4; j++) {
        int idx = i0 + j;
        if (idx < NBINS3) { off[idx] = run; cursors[idx] = run; }
        run += v[j];
    }
}

// ---- scatter: atomic-free (rank precomputed), fire-and-forget 8B records
__global__ __launch_bounds__(THREADS) void scatter_kernel(
    const int* __restrict__ dst, const int* __restrict__ src,
    const int* __restrict__ rel, const float* __restrict__ ew,
    const int* __restrict__ rank, const int* __restrict__ off,
    uint2* __restrict__ rec) {
    int i = blockIdx.x * 256 + threadIdx.x;        // 3125*256 = 800000 exactly
    int d = dst[i];
    int pos = off[d] + rank[i];
    uint2 v;
    v.x = (unsigned)(src[i] * 8 + rel[i]);         // src < 2^19, rel < 8
    v.y = __float_as_uint(ew[i]);
    rec[pos] = v;
}

// ---- agg: wave per dst; SEQUENTIAL rec reads; random featH reads (12.8MB region)
// accumulate h[8][128] in 16 f32 regs/lane (round-6 proven layout), MLP=4 edges.
__global__ __launch_bounds__(THREADS) void agg_kernel(
    const half_t* __restrict__ featH, const uint2* __restrict__ rec,
    const int* __restrict__ off, half_t* __restrict__ h) {
    int g = blockIdx.x * 4 + (threadIdx.x >> 6);   // 12500 blocks -> g < 50000
    int lane = threadIdx.x & 63;
    int beg = off[g], end = off[g + 1];

    float a0x = 0.f, a0y = 0.f, a1x = 0.f, a1y = 0.f;
    float a2x = 0.f, a2y = 0.f, a3x = 0.f, a3y = 0.f;
    float a4x = 0.f, a4y = 0.f, a5x = 0.f, a5y = 0.f;
    float a6x = 0.f, a6y = 0.f, a7x = 0.f, a7y = 0.f;

    const half_t* fb = featH + lane * 2;

#define ACCUM(RE, W, F) do {                                   \
        float wx_ = (W) * (float)(F)[0];                       \
        float wy_ = (W) * (float)(F)[1];                       \
        switch (RE) {                                          \
            case 0: a0x += wx_; a0y += wy_; break;             \
            case 1: a1x += wx_; a1y += wy_; break;             \
            case 2: a2x += wx_; a2y += wy_; break;             \
            case 3: a3x += wx_; a3y += wy_; break;             \
            case 4: a4x += wx_; a4y += wy_; break;             \
            case 5: a5x += wx_; a5y += wy_; break;             \
            case 6: a6x += wx_; a6y += wy_; break;             \
            default: a7x += wx_; a7y += wy_; break;            \
        } } while (0)

    int e = beg;
    for (; e + 4 <= end; e += 4) {                 // 4 independent featH reads in flight
        uint2 r0 = rec[e], r1 = rec[e + 1], r2 = rec[e + 2], r3 = rec[e + 3];
        half2v f0 = *(const half2v*)(fb + (size_t)(r0.x >> 3) * 128);
        half2v f1 = *(const half2v*)(fb + (size_t)(r1.x >> 3) * 128);
        half2v f2 = *(const half2v*)(fb + (size_t)(r2.x >> 3) * 128);
        half2v f3 = *(const half2v*)(fb + (size_t)(r3.x >> 3) * 128);
        ACCUM(r0.x & 7, __uint_as_float(r0.y), f0);
        ACCUM(r1.x & 7, __uint_as_float(r1.y), f1);
        ACCUM(r2.x & 7, __uint_as_float(r2.y), f2);
        ACCUM(r3.x & 7, __uint_as_float(r3.y), f3);
    }
    for (; e < end; e++) {
        uint2 r0 = rec[e];
        half2v f0 = *(const half2v*)(fb + (size_t)(r0.x >> 3) * 128);
        ACCUM(r0.x & 7, __uint_as_float(r0.y), f0);
    }
#undef ACCUM

    half_t* hb = h + (size_t)g * 1024 + lane * 2;  // round-6 proven store layout
    *(half2v*)(hb + 0 * 128) = (half2v){(half_t)a0x, (half_t)a0y};
    *(half2v*)(hb + 1 * 128) = (half2v){(half_t)a1x, (half_t)a1y};
    *(half2v*)(hb + 2 * 128) = (half2v){(half_t)a2x, (half_t)a2y};
    *(half2v*)(hb + 3 * 128) = (half2v){(half_t)a3x, (half_t)a3y};
    *(half2v*)(hb + 4 * 128) = (half2v){(half_t)a4x, (half_t)a4y};
    *(half2v*)(hb + 5 * 128) = (half2v){(half_t)a5x, (half_t)a5y};
    *(half2v*)(hb + 6 * 128) = (half2v){(half_t)a6x, (half_t)a6y};
    *(half2v*)(hb + 7 * 128) = (half2v){(half_t)a7x, (half_t)a7y};
}

// ---- gemm2 (round 8): barrier-free wave tiles, no LDS
// Each wave: 32 dsts x 64 cols, K=1024 in 8 chunks.
//   a-frag: WfT[(n0+nt*16+l16)*1024 + kc*128+kk*32+q*8]   (L2-hot, 256KB)
//   b-frag: h[(d0+ms*16+l16)*1024 + same k]                (own rows)
//   store : out[d*128 + n0 + nt*16 + q*4 + j] = acc[ms][nt][j]
// Per-lane element mapping byte-identical to the round-6/7 proven gemm2.
#define G2_TILES 3126                              // 1563 m-groups x 2 n-halves
#define G2_BLOCKS ((G2_TILES + 3) / 4)             // 782
template<bool GUARD>
__device__ __forceinline__ void gemm2w_body(const half_t* __restrict__ h,
                                            const half_t* __restrict__ WfT,
                                            float* __restrict__ out,
                                            int d0, int n0, int lane) {
    const int q = lane >> 4, l16 = lane & 15;
    const int dA = d0 + l16, dB = d0 + 16 + l16;
    const bool okA = !GUARD || dA < N_NODES;
    const bool okB = !GUARD || dB < N_NODES;
    const half_t* hA = h + (size_t)dA * 1024;
    const half_t* hB = h + (size_t)dB * 1024;
    const half_t* Wl = WfT + (size_t)l16 * 1024;   // + (n0+nt*16)*1024 per frag

    floatx4 acc[2][4];
    #pragma unroll
    for (int ms = 0; ms < 2; ms++)
        #pragma unroll
        for (int nt = 0; nt < 4; nt++) acc[ms][nt] = (floatx4){0.f, 0.f, 0.f, 0.f};

    #pragma unroll 1
    for (int kc = 0; kc < 8; kc++) {
        const int ko = kc * 128 + q * 8;
        half8 a[4][4], bA[4], bB[4];
        #pragma unroll
        for (int kk = 0; kk < 4; kk++) {
            uint4 vA = {0u, 0u, 0u, 0u}, vB = {0u, 0u, 0u, 0u};
            if (okA) vA = *(const uint4*)(hA + ko + kk * 32);
            if (okB) vB = *(const uint4*)(hB + ko + kk * 32);
            bA[kk] = *(half8*)&vA;
            bB[kk] = *(half8*)&vB;
            #pragma unroll
            for (int nt = 0; nt < 4; nt++)
                a[nt][kk] = *(const half8*)(Wl + (size_t)(n0 + nt * 16) * 1024 + ko + kk * 32);
        }
        #pragma unroll
        for (int kk = 0; kk < 4; kk++)
            #pragma unroll
            for (int nt = 0; nt < 4; nt++) {
                acc[0][nt] = __builtin_amdgcn_mfma_f32_16x16x32_f16(a[nt][kk], bA[kk], acc[0][nt], 0, 0, 0);
                acc[1][nt] = __builtin_amdgcn_mfma_f32_16x16x32_f16(a[nt][kk], bB[kk], acc[1][nt], 0, 0, 0);
            }
    }

    if (okA) {
        float* ob = out + (size_t)dA * 128 + n0;
        #pragma unroll
        for (int nt = 0; nt < 4; nt++) {
            float4 v;
            v.x = acc[0][nt][0]; v.y = acc[0][nt][1]; v.z = acc[0][nt][2]; v.w = acc[0][nt][3];
            *(float4*)(ob + nt * 16 + q * 4) = v;
        }
    }
    if (okB) {
        float* ob = out + (size_t)dB * 128 + n0;
        #pragma unroll
        for (int nt = 0; nt < 4; nt++) {
            float4 v;
            v.x = acc[1][nt][0]; v.y = acc[1][nt][1]; v.z = acc[1][nt][2]; v.w = acc[1][nt][3];
            *(float4*)(ob + nt * 16 + q * 4) = v;
        }
    }
}

__global__ __launch_bounds__(THREADS) void gemm2_kernel(
    const half_t* __restrict__ h, const half_t* __restrict__ WfT,
    float* __restrict__ out) {
    int w = blockIdx.x * 4 + (threadIdx.x >> 6);
    if (w >= G2_TILES) return;
    int lane = threadIdx.x & 63;
    int mg = w >> 1, nh = w & 1;
    int d0 = mg * 32, n0 = nh * 64;
    if (d0 + 32 <= N_NODES)
        gemm2w_body<false>(h, WfT, out, d0, n0, lane);
    else
        gemm2w_body<true>(h, WfT, out, d0, n0, lane);
}

// ---- fallback (tiny ws): wave-per-edge direct with atomics
__global__ void naive_kernel(const float* __restrict__ feat, const float* __restrict__ rel_emb,
                             const float* __restrict__ ew, const int* __restrict__ src,
                             const int* __restrict__ dst, const int* __restrict__ rel,
                             float* __restrict__ out) {
    int wave = (blockIdx.x * blockDim.x + threadIdx.x) >> 6;
    int lane = threadIdx.x & 63;
    if (wave >= N_EDGES) return;
    const float* f = feat + (size_t)src[wave] * IN_DIM;
    const float* W = rel_emb + (size_t)rel[wave] * IN_DIM * OUT_DIM;
    float w = ew[wave];
    float a0 = 0.f, a1 = 0.f;
    for (int k = 0; k < IN_DIM; k++) {
        float fv = f[k];
        a0 += fv * W[k * OUT_DIM + lane];
        a1 += fv * W[k * OUT_DIM + 64 + lane];
    }
    int d = dst[wave];
    atomicAdd(&out[(size_t)d * OUT_DIM + lane], a0 * w);
    atomicAdd(&out[(size_t)d * OUT_DIM + 64 + lane], a1 * w);
}

extern "C" void kernel_launch(void* const* d_in, const int* in_sizes, int n_in,
                              void* d_out, int out_size, void* d_ws, size_t ws_size,
                              hipStream_t stream) {
    const float* feat    = (const float*)d_in[0];
    const float* rel_emb = (const float*)d_in[1];
    const float* ew      = (const float*)d_in[2];
    const int*   src     = (const int*)d_in[3];
    const int*   dst     = (const int*)d_in[4];
    const int*   rel     = (const int*)d_in[5];
    float* out = (float*)d_out;

    if (ws_size >= WS_NEED) {
        char* ws = (char*)d_ws;
        half_t* h    = (half_t*)(ws + WS_H);
        half_t* WfT  = (half_t*)(ws + WS_WFT);
        uint2*  rec  = (uint2*)(ws + WS_REC);
        int*    off  = (int*)(ws + WS_OFF);
        int*    hist = (int*)(ws + WS_HIST);
        int*    bsum = (int*)(ws + WS_BSUM);
        // d_out scratch (dead until gemm2 writes it)
        int*    rank  = (int*)((char*)d_out + DO_RANK);
        half_t* featH = (half_t*)((char*)d_out + DO_FEATH);

        hipMemsetAsync(hist, 0, (size_t)NBINS3 * 4, stream);
        prep_kernel<<<PREP_BLOCKS, THREADS, 0, stream>>>(rel_emb, WfT, feat, featH,
                                                         dst, hist, rank);
        scan1_kernel<<<NB3, 256, 0, stream>>>(hist, bsum);
        scan2_kernel<<<1, 64, 0, stream>>>(bsum, off);
        scan3_kernel<<<NB3, 256, 0, stream>>>(hist, bsum, off, hist);  // cursors unused
        scatter_kernel<<<RANK_BLOCKS, THREADS, 0, stream>>>(dst, src, rel, ew,
                                                            rank, off, rec);
        agg_kernel<<<N_NODES / 4, THREADS, 0, stream>>>(featH, rec, off, h);
        gemm2_kernel<<<G2_BLOCKS, THREADS, 0, stream>>>(h, WfT, out);
    } else {
        hipMemsetAsync(d_out, 0, (size_t)out_size * sizeof(float), stream);
        const long long total = (long long)N_EDGES * 64;
        const int blocks = (int)((total + THREADS - 1) / THREADS);
        naive_kernel<<<blocks, THREADS, 0, stream>>>(feat, rel_emb, ew, src, dst, rel, out);
    }
}